// Round 1
// 135.592 us; speedup vs baseline: 1.0308x; 1.0308x over previous
//
#include <hip/hip_runtime.h>
#include <hip/hip_bf16.h>

#define B_SZ 4096
#define DZ   512
#define H_SZ 2048
#define DY   10

// c_k = C(64,k)/64^k  (binomial coefficients of (1+u/64)^64), c0=c1=1
#define C2 0.4921875f
#define C3 0.158935546875f
#define C4 0.037872314453125f
#define C5 ((float)(7624512.0/1073741824.0))
#define C6 ((float)(74974368.0/68719476736.0))

typedef __attribute__((ext_vector_type(8))) __bf16 bf16x8;
typedef __attribute__((ext_vector_type(4))) float  f32x4;
typedef __attribute__((ext_vector_type(8))) unsigned short us8;

__device__ inline unsigned short f2bf(float f) {
    unsigned u = __float_as_uint(f);
    u += 0x7fffu + ((u >> 16) & 1u);   // RTNE
    return (unsigned short)(u >> 16);
}
__device__ inline float bf2f(unsigned short s) {
    return __uint_as_float(((unsigned)s) << 16);
}

// global -> LDS direct 16B copy. LDS dest is wave-uniform base + lane*16
// (HW semantics), so callers pre-apply the inverse XOR swizzle on the
// per-lane GLOBAL address and keep the LDS side linear (rule #21 pattern).
__device__ __forceinline__ void gl16(const void* g, void* l) {
    __builtin_amdgcn_global_load_lds(
        (const __attribute__((address_space(1))) unsigned int*)(size_t)g,
        (__attribute__((address_space(3))) unsigned int*)(unsigned)(size_t)l,
        16, 0, 0);
}

union SqSmem {
    struct { unsigned short A[64 * 64]; unsigned short B[64 * 64]; } s; // 16 KB
    float epi[64 * 68];                                                 // 17.4 KB
};

// Stage a 64x64 bf16 tile (rows row_base..row_base+63, k-cols kt*64..)
// into LDS with layout lds[row*64 + (cc^(row&7))*8] via global_load_lds.
// Linear LDS chunk o: row=o>>3, ccs=o&7 -> source cc = ccs^(row&7).
__device__ __forceinline__ void stage64(const unsigned short* __restrict__ src,
                                        unsigned short* lds, int row_base,
                                        int kt, int t) {
    const int w = t >> 6, lane = t & 63;
#pragma unroll
    for (int i = 0; i < 2; ++i) {
        int o = w * 128 + i * 64 + lane;
        int row = o >> 3, cc = (o & 7) ^ (row & 7);
        gl16(&src[(size_t)(row_base + row) * 512 + kt * 64 + cc * 8],
             &lds[(size_t)(w * 128 + i * 64) * 8]);
    }
}

#define MFMA_STEP(acc)                                                        \
    {                                                                         \
        _Pragma("unroll")                                                     \
        for (int ks = 0; ks < 2; ++ks) {                                      \
            bf16x8 af[2], bfr[2];                                             \
            _Pragma("unroll")                                                 \
            for (int i = 0; i < 2; ++i) {                                     \
                int ra = wm + i * 16 + l16, ca = (ks * 4 + quad) ^ (ra & 7);  \
                af[i] = *(const bf16x8*)&sm.s.A[ra * 64 + ca * 8];            \
                int rb = wn + i * 16 + l16, cb = (ks * 4 + quad) ^ (rb & 7);  \
                bfr[i] = *(const bf16x8*)&sm.s.B[rb * 64 + cb * 8];           \
            }                                                                 \
            _Pragma("unroll")                                                 \
            for (int i = 0; i < 2; ++i)                                       \
                _Pragma("unroll")                                             \
                for (int j = 0; j < 2; ++j)                                   \
                    acc[i][j] = __builtin_amdgcn_mfma_f32_16x16x32_bf16(      \
                        af[i], bfr[j], acc[i][j], 0, 0, 0);                   \
        }                                                                     \
    }

#define ACC_TO_EPI(acc)                                                       \
    {                                                                         \
        _Pragma("unroll")                                                     \
        for (int i = 0; i < 2; ++i)                                           \
            _Pragma("unroll")                                                 \
            for (int j = 0; j < 2; ++j)                                       \
                _Pragma("unroll")                                             \
                for (int rr = 0; rr < 4; ++rr)                                \
                    sm.epi[(wm + i * 16 + quad * 4 + rr) * 68 +               \
                           wn + j * 16 + l16] = acc[i][j][rr];                \
        __syncthreads();                                                      \
    }

// ---------------------------------------------------------------------------
// gemm64_mfma: 64x64 tile of (Arows)·(Brows)^T, bf16 sources, K=512 -> sm.epi
// staging now via global_load_lds (linear LDS dest, pre-swizzled global src)
// ---------------------------------------------------------------------------
__device__ inline void gemm64_mfma(const unsigned short* __restrict__ Arows,
                                   const unsigned short* __restrict__ Brows,
                                   int m0, int n0, int t, SqSmem& sm) {
    const int lane = t & 63, w = t >> 6, quad = lane >> 4, l16 = lane & 15;
    const int wm = (w & 1) * 32, wn = (w >> 1) * 32;
    f32x4 acc[2][2];
#pragma unroll
    for (int i = 0; i < 2; ++i)
#pragma unroll
        for (int j = 0; j < 2; ++j) acc[i][j] = (f32x4){0.f, 0.f, 0.f, 0.f};
    for (int kt = 0; kt < 8; ++kt) {
        stage64(Arows, sm.s.A, m0, kt, t);
        stage64(Brows, sm.s.B, n0, kt, t);
        __syncthreads();
        MFMA_STEP(acc)
        __syncthreads();
    }
    ACC_TO_EPI(acc)
}

// ---------------------------------------------------------------------------
// gemm64_f32src: 64x64 tile of Arows·Bsrc (BOTH fp32 row-major, stride 512),
// staged with inline f2bf; B transposed via scalar scatter (r5/r7-proven).
// ---------------------------------------------------------------------------
__device__ inline void gemm64_f32src(const float* __restrict__ Arows,
                                     const float* __restrict__ Bsrc,
                                     int m0, int n0, int t, SqSmem& sm) {
    const int lane = t & 63, w = t >> 6, quad = lane >> 4, l16 = lane & 15;
    const int wm = (w & 1) * 32, wn = (w >> 1) * 32;
    const int r = t >> 2, cq = t & 3;
    f32x4 acc[2][2];
#pragma unroll
    for (int i = 0; i < 2; ++i)
#pragma unroll
        for (int j = 0; j < 2; ++j) acc[i][j] = (f32x4){0.f, 0.f, 0.f, 0.f};
    for (int kt = 0; kt < 8; ++kt) {
        float va[16];
#pragma unroll
        for (int u = 0; u < 4; ++u) {
            float4 f = *(const float4*)&Arows[(size_t)(m0 + r) * 512 + kt * 64 + cq * 16 + u * 4];
            va[u * 4 + 0] = f.x; va[u * 4 + 1] = f.y;
            va[u * 4 + 2] = f.z; va[u * 4 + 3] = f.w;
        }
#pragma unroll
        for (int j2 = 0; j2 < 2; ++j2) {
            us8 h;
#pragma unroll
            for (int j = 0; j < 8; ++j) h[j] = f2bf(va[j2 * 8 + j]);
            int cc = cq * 2 + j2;
            *(us8*)&sm.s.A[r * 64 + (cc ^ (r & 7)) * 8] = h;
        }
#pragma unroll
        for (int u = 0; u < 4; ++u) {
            float4 f = *(const float4*)&Bsrc[(size_t)(kt * 64 + r) * 512 + n0 + cq * 16 + u * 4];
            float vv[4] = {f.x, f.y, f.z, f.w};
#pragma unroll
            for (int j = 0; j < 4; ++j) {
                int n = cq * 16 + u * 4 + j;
                sm.s.B[n * 64 + ((r >> 3) ^ (n & 7)) * 8 + (r & 7)] = f2bf(vv[j]);
            }
        }
        __syncthreads();
        MFMA_STEP(acc)
        __syncthreads();
    }
    ACC_TO_EPI(acc)
}

__device__ inline void epi_out_bf(unsigned short* __restrict__ dst, int m0,
                                  int n0, int t, SqSmem& sm) {
    const int r = t >> 2, cq = t & 3;
    us8 h0, h1;
#pragma unroll
    for (int j = 0; j < 8; ++j) {
        h0[j] = f2bf(sm.epi[r * 68 + cq * 16 + j]);
        h1[j] = f2bf(sm.epi[r * 68 + cq * 16 + 8 + j]);
    }
    *(us8*)&dst[(size_t)(m0 + r) * 512 + n0 + cq * 16]     = h0;
    *(us8*)&dst[(size_t)(m0 + r) * 512 + n0 + cq * 16 + 8] = h1;
}
__device__ inline void epi_out_bfT(unsigned short* __restrict__ dst, int m0,
                                   int n0, int t, SqSmem& sm) {
    const int cf = t >> 2, rq = t & 3;
    us8 o0, o1;
#pragma unroll
    for (int i = 0; i < 8; ++i) {
        o0[i] = f2bf(sm.epi[(rq * 16 + i) * 68 + cf]);
        o1[i] = f2bf(sm.epi[(rq * 16 + 8 + i) * 68 + cf]);
    }
    *(us8*)&dst[(size_t)(n0 + cf) * 512 + m0 + rq * 16]     = o0;
    *(us8*)&dst[(size_t)(n0 + cf) * 512 + m0 + rq * 16 + 8] = o1;
}

// ===========================================================================
// k_s1 (grid 384): x->bf16; y=b2; 0..63: A2 = f32src(A,A); 64..127: AT_bf;
// 128..383: U1 = f32src(W1,A)    (r7/r11-proven)
// ===========================================================================
__global__ __launch_bounds__(256) void k_s1(
    const float* __restrict__ A, const float* __restrict__ x,
    const float* __restrict__ W1, const float* __restrict__ b2,
    unsigned short* __restrict__ A2_bf, unsigned short* __restrict__ A2T_bf,
    unsigned short* __restrict__ AT_bf, unsigned short* __restrict__ U1_bf,
    unsigned short* __restrict__ x_bf, float* __restrict__ y) {
    __shared__ SqSmem sm;
    const int b = blockIdx.x, t = threadIdx.x;
    const int gid = b * 256 + t;                 // 0 .. 98303

    const float4* x4 = (const float4*)x;
#pragma unroll
    for (int i = 0; i < 3; ++i) {
        int id = gid + i * 98304;
        if (id < 262144) {
            float4 v0 = x4[(size_t)id * 2], v1 = x4[(size_t)id * 2 + 1];
            us8 o;
            o[0] = f2bf(v0.x); o[1] = f2bf(v0.y); o[2] = f2bf(v0.z); o[3] = f2bf(v0.w);
            o[4] = f2bf(v1.x); o[5] = f2bf(v1.y); o[6] = f2bf(v1.z); o[7] = f2bf(v1.w);
            *(us8*)&x_bf[(size_t)id * 8] = o;
        }
    }
    if (gid < B_SZ * DY) y[gid] = b2[gid % 10];

    if (b < 64) {
        const int m0 = (b >> 3) * 64, n0 = (b & 7) * 64;
        gemm64_f32src(A, A, m0, n0, t, sm);
        epi_out_bf(A2_bf, m0, n0, t, sm);
        epi_out_bfT(A2T_bf, m0, n0, t, sm);
    } else if (b < 128) {
        const int bb = b - 64, m0 = (bb >> 3) * 64, n0 = (bb & 7) * 64;
        const int r = t >> 2, cq = t & 3;
#pragma unroll
        for (int u = 0; u < 4; ++u) {
            float4 f = *(const float4*)&A[(size_t)(m0 + r) * 512 + n0 + cq * 16 + u * 4];
            sm.epi[r * 68 + cq * 16 + u * 4 + 0] = f.x;
            sm.epi[r * 68 + cq * 16 + u * 4 + 1] = f.y;
            sm.epi[r * 68 + cq * 16 + u * 4 + 2] = f.z;
            sm.epi[r * 68 + cq * 16 + u * 4 + 3] = f.w;
        }
        __syncthreads();
        epi_out_bfT(AT_bf, m0, n0, t, sm);
    } else {
        const int bb = b - 128, m0 = (bb >> 3) * 64, n0 = (bb & 7) * 64;
        gemm64_f32src(W1, A, m0, n0, t, sm);     // U1 = W1·A
        epi_out_bf(U1_bf, m0, n0, t, sm);
    }
}

// ===========================================================================
// k_s2 (grid 576): 0..63: A3 = A2·A -> A3T_bf ; 64..319: U2 = U1·A ;
// 320..575: U3 = U1·A2    (r7/r11-proven; staging -> global_load_lds)
// ===========================================================================
__global__ __launch_bounds__(256) void k_s2(
    const unsigned short* __restrict__ A2_bf,
    const unsigned short* __restrict__ A2T_bf,
    const unsigned short* __restrict__ AT_bf,
    const unsigned short* __restrict__ U1_bf,
    unsigned short* __restrict__ A3T_bf, unsigned short* __restrict__ U2_bf,
    unsigned short* __restrict__ U3_bf) {
    __shared__ SqSmem sm;
    const int b = blockIdx.x, t = threadIdx.x;
    if (b < 64) {
        const int m0 = (b >> 3) * 64, n0 = (b & 7) * 64;
        gemm64_mfma(A2_bf, AT_bf, m0, n0, t, sm);
        epi_out_bfT(A3T_bf, m0, n0, t, sm);
    } else if (b < 320) {
        const int bb = b - 64, m0 = (bb >> 3) * 64, n0 = (bb & 7) * 64;
        gemm64_mfma(U1_bf, AT_bf, m0, n0, t, sm);
        epi_out_bf(U2_bf, m0, n0, t, sm);
    } else {
        const int bb = b - 320, m0 = (bb >> 3) * 64, n0 = (bb & 7) * 64;
        gemm64_mfma(U1_bf, A2T_bf, m0, n0, t, sm);
        epi_out_bf(U3_bf, m0, n0, t, sm);
    }
}

// ===========================================================================
// k_s3 (grid 256): w1f = bf16( W1 + U1 + c2U2 + c3U3
//                              + (c4U1 + c5U2 + c6U3)·A3 )
// B-side staging -> global_load_lds; A-side keeps the f2bf combine path.
// ===========================================================================
__global__ __launch_bounds__(256) void k_s3(
    const float* __restrict__ W1, const unsigned short* __restrict__ U1_bf,
    const unsigned short* __restrict__ U2_bf,
    const unsigned short* __restrict__ U3_bf,
    const unsigned short* __restrict__ A3T_bf,
    unsigned short* __restrict__ w1f) {
    __shared__ SqSmem sm;
    const int b = blockIdx.x, t = threadIdx.x;
    const int m0 = (b >> 3) * 64, n0 = (b & 7) * 64;
    const int lane = t & 63, w = t >> 6, quad = lane >> 4, l16 = lane & 15;
    const int wm = (w & 1) * 32, wn = (w >> 1) * 32;
    f32x4 acc[2][2];
#pragma unroll
    for (int i = 0; i < 2; ++i)
#pragma unroll
        for (int j = 0; j < 2; ++j) acc[i][j] = (f32x4){0.f, 0.f, 0.f, 0.f};
    for (int kt = 0; kt < 8; ++kt) {
        stage64(A3T_bf, sm.s.B, n0, kt, t);
#pragma unroll
        for (int c = 0; c < 2; ++c) {
            int idx = c * 256 + t, row = idx >> 3, cc = idx & 7;
            int ccs = cc ^ (row & 7);
            size_t ga = (size_t)(m0 + row) * 512 + kt * 64 + cc * 8;
            us8 u1 = *(const us8*)&U1_bf[ga];
            us8 u2 = *(const us8*)&U2_bf[ga];
            us8 u3 = *(const us8*)&U3_bf[ga];
            us8 g;
#pragma unroll
            for (int j = 0; j < 8; ++j)
                g[j] = f2bf(C4 * bf2f(u1[j]) + C5 * bf2f(u2[j]) + C6 * bf2f(u3[j]));
            *(us8*)&sm.s.A[row * 64 + ccs * 8] = g;
        }
        __syncthreads();
        MFMA_STEP(acc)
        __syncthreads();
    }
    ACC_TO_EPI(acc)
    const int r = t >> 2, cq = t & 3;
    size_t gbase = (size_t)(m0 + r) * 512 + n0 + cq * 16;
    us8 u1a = *(const us8*)&U1_bf[gbase], u1b = *(const us8*)&U1_bf[gbase + 8];
    us8 u2a = *(const us8*)&U2_bf[gbase], u2b = *(const us8*)&U2_bf[gbase + 8];
    us8 u3a = *(const us8*)&U3_bf[gbase], u3b = *(const us8*)&U3_bf[gbase + 8];
    us8 h0, h1;
#pragma unroll
    for (int u = 0; u < 2; ++u) {
        float4 wv = *(const float4*)&W1[gbase + u * 4];
        float4 wv2 = *(const float4*)&W1[gbase + 8 + u * 4];
#pragma unroll
        for (int j = 0; j < 4; ++j) {
            int e = u * 4 + j;
            float wj = (j == 0 ? wv.x : j == 1 ? wv.y : j == 2 ? wv.z : wv.w);
            float wj2 = (j == 0 ? wv2.x : j == 1 ? wv2.y : j == 2 ? wv2.z : wv2.w);
            h0[e] = f2bf(wj + bf2f(u1a[e]) + C2 * bf2f(u2a[e]) +
                         C3 * bf2f(u3a[e]) + sm.epi[r * 68 + cq * 16 + e]);
            h1[e] = f2bf(wj2 + bf2f(u1b[e]) + C2 * bf2f(u2b[e]) +
                         C3 * bf2f(u3b[e]) + sm.epi[r * 68 + cq * 16 + 8 + e]);
        }
    }
    *(us8*)&w1f[gbase]     = h0;
    *(us8*)&w1f[gbase + 8] = h1;
}

// ===========================================================================
// mlp v8: 128x128 tiles (m97 geometry), grid (32,16) = 512 blocks,
// global_load_lds staging (linear LDS dest + inverse-swizzled global src),
// acc[4][4]/wave. Epilogue: bias+relu -> LDS h (stride 136), h@W2^T MFMA,
// atomicAdd into y (164K atomics total).
// ===========================================================================
union SmemU {
    struct { unsigned short A[128 * 64]; unsigned short B[128 * 64]; } s; // 32 KB
    struct { unsigned short h[128 * 136]; } e;                            // 34.8 KB
};

__global__ __launch_bounds__(256) void mlp_kernel(
    const unsigned short* __restrict__ x_bf,
    const unsigned short* __restrict__ w1f,
    const float* __restrict__ b1, const float* __restrict__ W2,
    float* __restrict__ y) {
    __shared__ SmemU sm;
    const int t    = threadIdx.x;
    const int lane = t & 63, w = t >> 6;
    const int quad = lane >> 4, l16 = lane & 15;
    const int wm = (w & 1) * 64, wn = (w >> 1) * 64;
    const int m0g = blockIdx.x * 128, n0g = blockIdx.y * 128;

    f32x4 acc[4][4];
#pragma unroll
    for (int i = 0; i < 4; ++i)
#pragma unroll
        for (int j = 0; j < 4; ++j) acc[i][j] = (f32x4){0.f, 0.f, 0.f, 0.f};

    for (int kt = 0; kt < 8; ++kt) {
        // A tile: 128x64 bf16 = 1024 chunks of 16B, 4 wave-loads per wave
#pragma unroll
        for (int i = 0; i < 4; ++i) {
            int o = w * 256 + i * 64 + lane;
            int row = o >> 3, cc = (o & 7) ^ (row & 7);
            gl16(&x_bf[(size_t)(m0g + row) * 512 + kt * 64 + cc * 8],
                 &sm.s.A[(size_t)(w * 256 + i * 64) * 8]);
        }
        // B tile: 128x64
#pragma unroll
        for (int i = 0; i < 4; ++i) {
            int o = w * 256 + i * 64 + lane;
            int row = o >> 3, cc = (o & 7) ^ (row & 7);
            gl16(&w1f[(size_t)(n0g + row) * 512 + kt * 64 + cc * 8],
                 &sm.s.B[(size_t)(w * 256 + i * 64) * 8]);
        }
        __syncthreads();
#pragma unroll
        for (int ks = 0; ks < 2; ++ks) {
            bf16x8 af[4], bfr[4];
#pragma unroll
            for (int i = 0; i < 4; ++i) {
                int ra = wm + i * 16 + l16, ca = (ks * 4 + quad) ^ (ra & 7);
                af[i] = *(const bf16x8*)&sm.s.A[ra * 64 + ca * 8];
                int rb = wn + i * 16 + l16, cb = (ks * 4 + quad) ^ (rb & 7);
                bfr[i] = *(const bf16x8*)&sm.s.B[rb * 64 + cb * 8];
            }
#pragma unroll
            for (int i = 0; i < 4; ++i)
#pragma unroll
                for (int j = 0; j < 4; ++j)
                    acc[i][j] = __builtin_amdgcn_mfma_f32_16x16x32_bf16(
                        af[i], bfr[j], acc[i][j], 0, 0, 0);
        }
        __syncthreads();
    }

    // ---- epilogue: bias + relu -> LDS h (m-major, stride 136) ----
    float bias[4];
#pragma unroll
    for (int j = 0; j < 4; ++j) bias[j] = b1[n0g + wn + j * 16 + l16];
#pragma unroll
    for (int i = 0; i < 4; ++i)
#pragma unroll
        for (int j = 0; j < 4; ++j)
#pragma unroll
            for (int r = 0; r < 4; ++r) {
                float h = acc[i][j][r] + bias[j];
                h = h > 0.f ? h : 0.f;
                sm.e.h[(wm + i * 16 + quad * 4 + r) * 136 + wn + j * 16 + l16] =
                    f2bf(h);
            }
    __syncthreads();

    // ---- y += h @ W2^T via MFMA: wave w owns m-rows [w*32, w*32+32) ----
    {
        bf16x8 wfrag[4];
#pragma unroll
        for (int kc = 0; kc < 4; ++kc) {
            us8 wb;
            if (l16 < DY) {
                const float* wp = &W2[(size_t)l16 * H_SZ + n0g + kc * 32 + quad * 8];
#pragma unroll
                for (int j = 0; j < 8; ++j) wb[j] = f2bf(wp[j]);
            } else {
#pragma unroll
                for (int j = 0; j < 8; ++j) wb[j] = 0;
            }
            wfrag[kc] = *(bf16x8*)&wb;
        }
#pragma unroll
        for (int hh = 0; hh < 2; ++hh) {
            const int mrow = w * 32 + hh * 16;
            f32x4 ay = (f32x4){0.f, 0.f, 0.f, 0.f};
#pragma unroll
            for (int kc = 0; kc < 4; ++kc) {
                bf16x8 af = *(const bf16x8*)&sm.e.h[(mrow + l16) * 136 +
                                                    kc * 32 + quad * 8];
                ay = __builtin_amdgcn_mfma_f32_16x16x32_bf16(af, wfrag[kc], ay,
                                                             0, 0, 0);
            }
            if (l16 < DY) {
#pragma unroll
                for (int r = 0; r < 4; ++r)
                    atomicAdd(&y[(size_t)(m0g + mrow + quad * 4 + r) * DY + l16],
                              ay[r]);
            }
        }
    }
}

// ===========================================================================
extern "C" void kernel_launch(void* const* d_in, const int* in_sizes, int n_in,
                              void* d_out, int out_size, void* d_ws, size_t ws_size,
                              hipStream_t stream) {
    const float* x  = (const float*)d_in[0];
    const float* A  = (const float*)d_in[1];
    const float* W1 = (const float*)d_in[2];
    const float* b1 = (const float*)d_in[3];
    const float* W2 = (const float*)d_in[4];
    const float* b2 = (const float*)d_in[5];
    float* y = (float*)d_out;

    char* ws = (char*)d_ws;
    const size_t HMB = 512u * 1024, MB = 1u << 20;
    unsigned short* AT_bf  = (unsigned short*)(ws);
    unsigned short* A2_bf  = (unsigned short*)(ws + 1 * HMB);
    unsigned short* A2T_bf = (unsigned short*)(ws + 2 * HMB);
    unsigned short* A3T_bf = (unsigned short*)(ws + 3 * HMB);
    unsigned short* U1_bf  = (unsigned short*)(ws + 2 * MB);   // 2 MB
    unsigned short* U2_bf  = (unsigned short*)(ws + 4 * MB);   // 2 MB
    unsigned short* U3_bf  = (unsigned short*)(ws + 6 * MB);   // 2 MB
    unsigned short* w1f    = (unsigned short*)(ws + 8 * MB);   // 2 MB
    unsigned short* x_bf   = (unsigned short*)(ws + 10 * MB);  // 4 MB

    k_s1<<<384, 256, 0, stream>>>(A, x, W1, b2, A2_bf, A2T_bf, AT_bf, U1_bf,
                                  x_bf, y);
    k_s2<<<576, 256, 0, stream>>>(A2_bf, A2T_bf, AT_bf, U1_bf, A3T_bf, U2_bf,
                                  U3_bf);
    k_s3<<<256, 256, 0, stream>>>(W1, U1_bf, U2_bf, U3_bf, A3T_bf, w1f);
    mlp_kernel<<<dim3(32, 16), dim3(256), 0, stream>>>(x_bf, w1f, b1, W2, y);
}